// Round 9
// baseline (343.021 us; speedup 1.0000x reference)
//
#include <hip/hip_runtime.h>

// DIAGNOSTIC ROUND (v9): v6 verbatim, main loop repeated REPEAT=3 times with
// identical (idempotent) outputs. Purpose: push the kernel dispatch above the
// ~124-132 us harness fills so its rocprof counters appear in the top-5 table
// (they've been hidden for 5 rounds). Next round branches on VALUBusy /
// hbm_gbps / OccupancyPercent. Bench dur regresses by design; v6 (248.3 us)
// is the committed best.
//
// Math (verified): out = relu(x @ (gamma*W3 + W4)^T), x:(B,20), M:(200,20).
// Floor: 210 MB write + 21 MB read => ~34-37 us. v6 kernel ~70 us.

#define BATCH          262144
#define DICT           20
#define COLS           200                        // NUM_HEADS * DICT
#define NTHREADS       256                        // 4 waves
#define ROWS_PER_BLOCK 128
#define ROWS_PER_WAVE  32
#define NBLOCKS        (BATCH / ROWS_PER_BLOCK)   // 2048
#define REPEAT         3                          // diagnostic multiplier

typedef float f32x4 __attribute__((ext_vector_type(4)));

__global__ __launch_bounds__(NTHREADS, 3)
void attn_v9_diag_kernel(const float* __restrict__ x,
                         const float* __restrict__ W3,
                         const float* __restrict__ W4,
                         const float* __restrict__ gamma,
                         float* __restrict__ out)
{
    __shared__ f32x4 ldsX[ROWS_PER_BLOCK * 5];   // 10 KB x tile

    const int t = threadIdx.x;

    const f32x4* xg = (const f32x4*)(x + (size_t)blockIdx.x * ROWS_PER_BLOCK * DICT);
    for (int i = t; i < ROWS_PER_BLOCK * 5; i += NTHREADS)
        ldsX[i] = __builtin_nontemporal_load(&xg[i]);
    __syncthreads();

    const int lane = t & 63;
    const int wv   = t >> 6;
    if (lane >= 50) return;

    const float g   = gamma[0];
    const int   cf4 = lane;

    f32x4 m[4][5];
#pragma unroll
    for (int c = 0; c < 4; ++c) {
        const f32x4* a = (const f32x4*)(W3 + (4 * cf4 + c) * DICT);
        const f32x4* b = (const f32x4*)(W4 + (4 * cf4 + c) * DICT);
#pragma unroll
        for (int k = 0; k < 5; ++k) {
            f32x4 p = a[k], q = b[k], r;
            r.x = fmaf(g, p.x, q.x); r.y = fmaf(g, p.y, q.y);
            r.z = fmaf(g, p.z, q.z); r.w = fmaf(g, p.w, q.w);
            m[c][k] = r;
        }
    }

    const int row0 = blockIdx.x * ROWS_PER_BLOCK + wv * ROWS_PER_WAVE;
    const f32x4* xl = &ldsX[wv * ROWS_PER_WAVE * 5];
    f32x4* op = (f32x4*)(out + (size_t)row0 * COLS) + cf4;

#define DOT4(ACC, XV)                                          \
    {                                                          \
        float* ap_ = (float*)&(ACC);                           \
        _Pragma("unroll")                                      \
        for (int c = 0; c < 4; ++c) {                          \
            float p0 = 0.f, p1 = 0.f;                          \
            _Pragma("unroll")                                  \
            for (int k = 0; k < 5; ++k) {                      \
                p0 = fmaf(m[c][k].x, (XV)[k].x, p0);           \
                p1 = fmaf(m[c][k].y, (XV)[k].y, p1);           \
                p0 = fmaf(m[c][k].z, (XV)[k].z, p0);           \
                p1 = fmaf(m[c][k].w, (XV)[k].w, p1);           \
            }                                                  \
            ap_[c] = fmaxf(p0 + p1, 0.f);                      \
        }                                                      \
    }

    for (int rep = 0; rep < REPEAT; ++rep) {
        f32x4 xv[5], xn[5];
#pragma unroll
        for (int k = 0; k < 5; ++k) xv[k] = xl[k];

        for (int r = 0; r < ROWS_PER_WAVE; r += 2) {
#pragma unroll
            for (int k = 0; k < 5; ++k) xn[k] = xl[(r + 1) * 5 + k];

            f32x4 acc0;
            DOT4(acc0, xv)
            __builtin_nontemporal_store(acc0, &op[(size_t)r * 50]);

            if (r + 2 < ROWS_PER_WAVE) {
#pragma unroll
                for (int k = 0; k < 5; ++k) xv[k] = xl[(r + 2) * 5 + k];
            }

            f32x4 acc1;
            DOT4(acc1, xn)
            __builtin_nontemporal_store(acc1, &op[(size_t)(r + 1) * 50]);
        }
        // Compiler-only barrier (no instructions emitted): prevents cross-rep
        // dead-store elimination / ds_read hoisting so each rep re-executes
        // the full main loop. Output values are identical across reps.
        asm volatile("" ::: "memory");
    }
#undef DOT4
}

extern "C" void kernel_launch(void* const* d_in, const int* in_sizes, int n_in,
                              void* d_out, int out_size, void* d_ws, size_t ws_size,
                              hipStream_t stream) {
    const float* x     = (const float*)d_in[0];
    // d_in[1] = W1, d_in[2] = W2 : mathematically unused (softmax over size-1 axis)
    const float* W3    = (const float*)d_in[3];
    const float* W4    = (const float*)d_in[4];
    const float* gamma = (const float*)d_in[5];
    float* out = (float*)d_out;

    attn_v9_diag_kernel<<<NBLOCKS, NTHREADS, 0, stream>>>(x, W3, W4, gamma, out);
}